// Round 3
// baseline (47.260 us; speedup 1.0000x reference)
//
#include <hip/hip_runtime.h>

// Problem constants (static per reference)
constexpr int B_DIM   = 32;
constexpr int M_EDGES = 4096;     // edges per batch
constexpr int F_DIM   = 64;
constexpr int N_ATOMS = 128;

constexpr int TOTAL_EDGES = B_DIM * M_EDGES;               // 131072
constexpr int CELLS       = B_DIM * N_ATOMS * N_ATOMS;     // 524288
constexpr int K_CAP       = 16;                            // max edges/cell (Poisson(0.25))

using f32x4 = __attribute__((ext_vector_type(4))) float;
using u32x4 = __attribute__((ext_vector_type(4))) unsigned int;

// ---------------------------------------------------------------------------
// Kernel 1: bin edges by destination cell.
// ---------------------------------------------------------------------------
__global__ __launch_bounds__(256) void bin_edges_kernel(
    const int* __restrict__ pair,          // [B, M, 2] int32
    int*       __restrict__ counts,        // [CELLS]
    unsigned int* __restrict__ list)       // [CELLS * K_CAP]
{
    const int e = blockIdx.x * 256 + threadIdx.x;   // grid == TOTAL_EDGES exactly
    const int2 ij = ((const int2*)pair)[e];         // vectorized (i, j) load
    const int b = e >> 12;                          // e / M_EDGES (4096 = 2^12)

    const int cell = (b << 14) + (ij.x << 7) + ij.y;  // b*N*N + i*N + j

    const int pos = atomicAdd(&counts[cell], 1);
    if (pos < K_CAP) list[cell * K_CAP + pos] = (unsigned int)e;
}

// ---------------------------------------------------------------------------
// Kernel 2: 16 threads per cell, one float4 of F each. Branchless 4-wide
// gather: unused entry ids are clamped to entry 0 so the speculative loads
// alias an already-fetched line (L1 hit, no extra HBM traffic) and all 4
// loads issue independently (no loop-carried latency chain). Output written
// exactly once via nontemporal store (write-once data; keep L2 for reads).
// ---------------------------------------------------------------------------
__global__ __launch_bounds__(256) void gather_write_kernel(
    const float*        __restrict__ edge,    // [B, M, F]
    const int*          __restrict__ counts,  // [CELLS]
    const unsigned int* __restrict__ list,    // [CELLS * K_CAP]
    float*              __restrict__ out)     // [B, N, N, F]
{
    const int tid  = blockIdx.x * 256 + threadIdx.x;
    const int cell = tid >> 4;          // 16 threads per cell
    const int q    = tid & 15;          // which float4 of the 64 features

    int cnt = counts[cell];             // broadcast across the 16 lanes
    cnt = cnt > K_CAP ? K_CAP : cnt;

    f32x4 acc = (f32x4)0.0f;

    if (cnt > 0) {
        const u32x4 e4 = *reinterpret_cast<const u32x4*>(list + (size_t)cell * K_CAP);
        const unsigned int i0 = e4.x;
        const unsigned int i1 = cnt > 1 ? e4.y : i0;   // clamp -> aliases i0's line
        const unsigned int i2 = cnt > 2 ? e4.z : i0;
        const unsigned int i3 = cnt > 3 ? e4.w : i0;

        const f32x4* ef = (const f32x4*)edge;
        // 4 independent in-bounds loads, all issued before any use.
        const f32x4 a0 = ef[(size_t)i0 * 16 + q];
        const f32x4 a1 = ef[(size_t)i1 * 16 + q];
        const f32x4 a2 = ef[(size_t)i2 * 16 + q];
        const f32x4 a3 = ef[(size_t)i3 * 16 + q];

        const float s1 = cnt > 1 ? 1.0f : 0.0f;
        const float s2 = cnt > 2 ? 1.0f : 0.0f;
        const float s3 = cnt > 3 ? 1.0f : 0.0f;

        acc = a0;
        acc += a1 * s1;   // fma blend, no branches
        acc += a2 * s2;
        acc += a3 * s3;

        if (cnt > 4) {    // ~3 cells expected in the whole problem
            const unsigned int* cl = list + (size_t)cell * K_CAP;
            for (int t = 4; t < cnt; ++t) {
                const unsigned int e = cl[t];
                acc += ef[(size_t)e * 16 + q];
            }
        }
    }

    __builtin_nontemporal_store(acc, (f32x4*)out + ((size_t)cell * 16 + q));
}

extern "C" void kernel_launch(void* const* d_in, const int* in_sizes, int n_in,
                              void* d_out, int out_size, void* d_ws, size_t ws_size,
                              hipStream_t stream) {
    const float* edge = (const float*)d_in[0];
    const int*   pair = (const int*)d_in[1];
    float*       out  = (float*)d_out;

    // Workspace layout: [0, 2 MiB) counts (int32 x CELLS),
    //                   [2 MiB, 34 MiB) edge lists (u32 x CELLS x K_CAP).
    int*          counts = (int*)d_ws;
    unsigned int* list   = (unsigned int*)((char*)d_ws + (size_t)CELLS * sizeof(int));

    // Counts are mutated every call; zero them each launch (2 MiB, cheap).
    hipMemsetAsync(counts, 0, (size_t)CELLS * sizeof(int), stream);

    // Pass 1: bin edges. 131072 edges -> 512 blocks.
    bin_edges_kernel<<<TOTAL_EDGES / 256, 256, 0, stream>>>(pair, counts, list);

    // Pass 2: gather + single write per output quad.
    gather_write_kernel<<<(CELLS * 16) / 256, 256, 0, stream>>>(edge, counts, list, out);
}